// Round 6
// baseline (281.820 us; speedup 1.0000x reference)
//
#include <hip/hip_runtime.h>
#include <hip/hip_bf16.h>

// GMLLM dual-stream self-attention, MI355X/gfx950.  Round 6:
//  - 2 kernels total: proj (reads f32 hs/W directly, epilogue packs lq/lk upper halves)
//    and attn. cast_hs/cast_w/pack_layout deleted -> shorter serial chain.
//  - attn: PV upgraded to x32 MFMA via wave-private P^T LDS staging (b64 writes,
//    b128 B-frag reads, LDP=72 bank-uniform). S^T register softmax kept.

typedef __attribute__((ext_vector_type(8))) short short8;   // 8 x bf16 MFMA A/B frag (x32)
typedef __attribute__((ext_vector_type(4))) float floatx4;  // MFMA C/D frag

#define LOG2E 1.4426950408889634f
#define QSCL 0.18033688011112042f   /* 0.125 * log2(e) */

static constexpr int Sn = 2048, Dn = 768, Hn = 12, BHn = 48;

__device__ __forceinline__ unsigned short f2bf(float f) {
  unsigned u = __float_as_uint(f);
  u += 0x7FFFu + ((u >> 16) & 1u);          // RNE
  return (unsigned short)(u >> 16);
}

// 8 f32 -> 8 bf16 (RNE) via packed cvt
__device__ __forceinline__ short8 cvt8(float4 a, float4 b) {
  union { __hip_bfloat162 h; int i; } u0, u1, u2, u3;
  u0.h = __float22bfloat162_rn(float2{a.x, a.y});
  u1.h = __float22bfloat162_rn(float2{a.z, a.w});
  u2.h = __float22bfloat162_rn(float2{b.x, b.y});
  u3.h = __float22bfloat162_rn(float2{b.z, b.w});
  short8 r;
  ((int*)&r)[0] = u0.i; ((int*)&r)[1] = u1.i;
  ((int*)&r)[2] = u2.i; ((int*)&r)[3] = u3.i;
  return r;
}

typedef const __attribute__((address_space(1))) unsigned int* gas_t;
typedef __attribute__((address_space(3))) unsigned int* las_t;
__device__ __forceinline__ void async16(const void* g, void* l) {
  // async 16B/lane global->LDS; LDS dest = wave-uniform base + lane*16
  __builtin_amdgcn_global_load_lds((gas_t)g, (las_t)l, 16, 0, 0);
}

// ---------------- QKV projection from f32: C[m,n] = sum_k X[m,k] W[n,k] + bias[n] ------------
// BK=64; f32 global loads -> packed-cvt -> ds_write_b128 (XOR-swizzled slots).
// z=0 -> Qc lower half (pre-scaled QSCL) + lq upper half; z=1 -> Kc + lk; z=2 -> Vt transposed.
__global__ __launch_bounds__(256, 2)
void proj_kernel(const float* __restrict__ X,    // [8192][768] f32 (hidden_states)
                 const float* __restrict__ Wq, const float* __restrict__ Wk,
                 const float* __restrict__ Wv,
                 const float* __restrict__ bq, const float* __restrict__ bk,
                 const float* __restrict__ bv,
                 const float* __restrict__ LQ, const float* __restrict__ LK,  // [B,S,768] f32
                 unsigned short* __restrict__ Qc, unsigned short* __restrict__ Kc,
                 unsigned short* __restrict__ Vt) {
  __shared__ __align__(16) unsigned short sMem[16384];   // 32KB: K-loop A|B, then epilogue tile
  unsigned short* const sA = sMem;                       // [128][64]
  unsigned short* const sB = sMem + 8192;                // [128][64]

  const int z = blockIdx.z;
  const float* W = (z == 0) ? Wq : (z == 1) ? Wk : Wv;
  const float* bias = (z == 0) ? bq : (z == 1) ? bk : bv;

  const int t = threadIdx.x;
  const int lane = t & 63, wave = t >> 6;
  const int wm = wave >> 1, wn = wave & 1;
  const int quad = lane >> 4, col15 = lane & 15;
  const int m0 = blockIdx.y * 128, n0 = blockIdx.x * 128;

  floatx4 acc[4][4];
#pragma unroll
  for (int i = 0; i < 4; i++)
#pragma unroll
    for (int j = 0; j < 4; j++) acc[i][j] = (floatx4){0.f, 0.f, 0.f, 0.f};

  for (int k0 = 0; k0 < Dn; k0 += 64) {
    // issue all f32 tile loads before the barrier (no LDS hazard)
    float4 xa[4][2], xb[4][2];
#pragma unroll
    for (int c = 0; c < 4; c++) {
      int idx = c * 256 + t;
      int row = idx >> 3, sl = idx & 7;
      int gd = sl ^ (row & 7);
      const float* pa = X + (size_t)(m0 + row) * Dn + k0 + gd * 8;
      const float* pb = W + (size_t)(n0 + row) * Dn + k0 + gd * 8;
      xa[c][0] = *(const float4*)pa; xa[c][1] = *(const float4*)(pa + 4);
      xb[c][0] = *(const float4*)pb; xb[c][1] = *(const float4*)(pb + 4);
    }
    __syncthreads();                                // prev iter frag reads done
#pragma unroll
    for (int c = 0; c < 4; c++) {
      int idx = c * 256 + t;
      int row = idx >> 3, sl = idx & 7;
      *(short8*)(sA + row * 64 + sl * 8) = cvt8(xa[c][0], xa[c][1]);
      *(short8*)(sB + row * 64 + sl * 8) = cvt8(xb[c][0], xb[c][1]);
    }
    __syncthreads();
#pragma unroll
    for (int kk = 0; kk < 2; kk++) {
      short8 af[4], bf[4];
      const int slot_ = ((kk * 4 + quad) ^ (col15 & 7)) * 8;
#pragma unroll
      for (int i = 0; i < 4; i++)
        af[i] = *(const short8*)(sA + (wm * 64 + i * 16 + col15) * 64 + slot_);
#pragma unroll
      for (int j = 0; j < 4; j++)
        bf[j] = *(const short8*)(sB + (wn * 64 + j * 16 + col15) * 64 + slot_);
#pragma unroll
      for (int i = 0; i < 4; i++)
#pragma unroll
        for (int j = 0; j < 4; j++)
          acc[i][j] = __builtin_amdgcn_mfma_f32_16x16x32_bf16(af[i], bf[j], acc[i][j], 0, 0, 0);
    }
  }

  __syncthreads();                                  // K-loop LDS reads done; reuse sMem as tile
  const int b = m0 >> 11;                           // blocks never cross batch boundary
  const int s0g = m0 & (Sn - 1);
  const int h0 = n0 >> 6;

  if (z < 2) {
    // ---- Q/K: LDS tile [m][128n], n XOR-swizzled by (m>>2)&3 on bits 4-5 ----
    const float scl = (z == 0) ? QSCL : 1.0f;
    unsigned short* dst0 = (z == 0) ? Qc : Kc;
#pragma unroll
    for (int j = 0; j < 4; j++) {
      int nl = wn * 64 + j * 16 + col15;
      float bias_n = bias[n0 + nl];
#pragma unroll
      for (int i = 0; i < 4; i++) {
        int mb = wm * 64 + i * 16 + quad * 4;
#pragma unroll
        for (int r = 0; r < 4; r++) {
          int m = mb + r;
          sMem[m * 128 + (nl ^ (((m >> 2) & 3) << 4))] = f2bf((acc[i][j][r] + bias_n) * scl);
        }
      }
    }
    __syncthreads();
    const float* lsrc = (z == 0) ? LQ : LK;
#pragma unroll
    for (int cc = 0; cc < 8; cc++) {                // lower half: 2048 16B chunks from LDS
      int idx = cc * 256 + t;
      int m = idx >> 4, piece = idx & 15;
      int h = h0 + (piece >> 3), d8 = piece & 7;
      short8 v = *(const short8*)(sMem + m * 128 + (piece ^ (((m >> 2) & 3) << 1)) * 8);
      *(short8*)(dst0 + ((size_t)(b * Hn + h) * Sn + s0g + m) * 128 + d8 * 8) = v;
    }
    // ---- upper half: pack layout stream (f32 -> bf16, scaled) ----
#pragma unroll
    for (int cc = 0; cc < 8; cc++) {
      int idx = cc * 256 + t;
      int m = idx >> 4, piece = idx & 15;
      int h = h0 + (piece >> 3), d8 = piece & 7;
      const float* p = lsrc + ((size_t)b * Sn + s0g + m) * Dn + n0 + piece * 8;
      float4 v0 = *(const float4*)p, v1 = *(const float4*)(p + 4);
      v0.x *= scl; v0.y *= scl; v0.z *= scl; v0.w *= scl;
      v1.x *= scl; v1.y *= scl; v1.z *= scl; v1.w *= scl;
      *(short8*)(dst0 + ((size_t)(b * Hn + h) * Sn + s0g + m) * 128 + 64 + d8 * 8) = cvt8(v0, v1);
    }
  } else {
    // ---- V: LDS tile [n][128m], m XOR-swizzled by n&7 on bits 4-6; packed b64 writes ----
#pragma unroll
    for (int j = 0; j < 4; j++) {
      int nl = wn * 64 + j * 16 + col15;
      float bias_n = bias[n0 + nl];
#pragma unroll
      for (int i = 0; i < 4; i++) {
        int mb = wm * 64 + i * 16 + quad * 4;
        ushort4 pk = make_ushort4(f2bf(acc[i][j][0] + bias_n), f2bf(acc[i][j][1] + bias_n),
                                  f2bf(acc[i][j][2] + bias_n), f2bf(acc[i][j][3] + bias_n));
        *(ushort4*)(sMem + nl * 128 + (mb ^ ((nl & 7) << 4))) = pk;
      }
    }
    __syncthreads();
#pragma unroll
    for (int cc = 0; cc < 8; cc++) {                // coalesced Vt rows (256B per 16 lanes)
      int idx = cc * 256 + t;
      int nl = idx >> 4, piece = idx & 15;
      int h = h0 + (nl >> 6), d = nl & 63;
      short8 v = *(const short8*)(sMem + nl * 128 + (piece ^ ((nl & 7) << 1)) * 8);
      *(short8*)(Vt + ((size_t)(b * Hn + h) * 64 + d) * Sn + s0g + piece * 8) = v;
    }
  }
}

// ---------------- flash attention, S^T formulation: 128 q-rows/block, KT=64 ----------------
// S^T = K·Q^T (x32). P = exp2(S^T+mask) packed b64 into wave-private P^T LDS rows,
// read back as x32 B-frags -> PV at full x32 rate. No inter-wave barrier for P.
__global__ __launch_bounds__(256, 3)
void attn_kernel(const unsigned short* __restrict__ Qc,  // [BH][S][128], pre-scaled by QSCL
                 const unsigned short* __restrict__ Kc,  // [BH][S][128]
                 const unsigned short* __restrict__ Vt,  // [BH][64][S]
                 const float* __restrict__ mask,         // [B][S]
                 float* __restrict__ out) {              // [B][S][768]
  constexpr int LDP = 72;                                // sP stride: 144B rows (16B-aligned, bank-uniform)
  __shared__ __align__(16) unsigned short sKc[64 * 128]; // swizzled, pad-free (16KB)
  __shared__ __align__(16) unsigned short sVt[64 * 64];  // swizzled, pad-free (8KB)
  __shared__ __align__(16) float sMask[Sn];              // whole mask row (8KB)
  __shared__ __align__(16) unsigned short sP[128 * LDP]; // P^T, wave-private rows (18KB)

  const int t = threadIdx.x;
  const int lane = t & 63, wave = t >> 6;
  const int quad = lane >> 4, col15 = lane & 15;

  // XCD-aware swizzle: all 16 q-blocks of one bh share id&7 (L2 K/V reuse)
  const int id = blockIdx.x;
  const int slot = id >> 3;
  const int bh = (id & 7) + 8 * (slot >> 4);
  const int q0 = (slot & 15) * 128;
  const int b = bh / Hn, h = bh % Hn;

  const float* mbase = mask + (size_t)b * Sn;
  // stage the whole mask row once (drained by the loop's first __syncthreads)
#pragma unroll
  for (int c = 0; c < 2; c++)
    async16(mbase + (c * 256 + wave * 64 + lane) * 4, sMask + (c * 256 + wave * 64) * 4);

  // Q fragments: 32 rows/wave x 128 k, registers for all 32 tiles (B-operand of S^T)
  short8 aq[2][4];
  const unsigned short* Qbase = Qc + ((size_t)bh * Sn + q0 + wave * 32) * 128;
#pragma unroll
  for (int jq = 0; jq < 2; jq++)
#pragma unroll
    for (int kk = 0; kk < 4; kk++)
      aq[jq][kk] = *(const short8*)(Qbase + (size_t)(jq * 16 + col15) * 128 + kk * 32 + quad * 8);

  floatx4 OT[4][2];                                // O^T[d-tile][q-tile]
#pragma unroll
  for (int i = 0; i < 4; i++) {
    OT[i][0] = (floatx4){0.f, 0.f, 0.f, 0.f};
    OT[i][1] = (floatx4){0.f, 0.f, 0.f, 0.f};
  }
  float lsum[2] = {0.f, 0.f};

  const unsigned short* Kbase = Kc + (size_t)bh * Sn * 128;
  const unsigned short* Vbase = Vt + (size_t)bh * 64 * Sn;

  const int krow = lane >> 4, kslot = lane & 15;  // sKc staging: 4 rows/call, 16 chunks/row
  const int vrow = lane >> 3, vslot = lane & 7;   // sVt staging: 8 rows/call, 8 chunks/row

  for (int kt = 0; kt < Sn / 64; kt++) {
    __syncthreads();                              // prev tile reads done before restage
#pragma unroll
    for (int c = 0; c < 4; c++) {                 // K tile 64x256B, swizzled
      int row = wave * 16 + c * 4 + krow;
      int g = (kslot & 8) | ((kslot ^ row) & 7);
      async16(Kbase + (size_t)(kt * 64 + row) * 128 + g * 8, sKc + (wave * 16 + c * 4) * 128);
    }
#pragma unroll
    for (int c = 0; c < 2; c++) {                 // V^T tile 64x128B, swizzled
      int row = wave * 16 + c * 8 + vrow;
      int g = vslot ^ (row & 7);
      async16(Vbase + (size_t)row * Sn + kt * 64 + g * 8, sVt + (wave * 16 + c * 8) * 64);
    }
    __syncthreads();

    // ---- S^T = K Q^T (log2-domain; QSCL*log2e folded into Q) ----
    floatx4 sacc[4][2];
#pragma unroll
    for (int jk = 0; jk < 4; jk++) {
      sacc[jk][0] = (floatx4){0.f, 0.f, 0.f, 0.f};
      sacc[jk][1] = (floatx4){0.f, 0.f, 0.f, 0.f};
#pragma unroll
      for (int kk = 0; kk < 4; kk++) {
        int gr = kk * 4 + quad;
        int slot_ = ((gr & 8) | ((gr ^ col15) & 7)) * 8;
        short8 kf = *(const short8*)(sKc + (jk * 16 + col15) * 128 + slot_);
        sacc[jk][0] = __builtin_amdgcn_mfma_f32_16x16x32_bf16(kf, aq[0][kk], sacc[jk][0], 0, 0, 0);
        sacc[jk][1] = __builtin_amdgcn_mfma_f32_16x16x32_bf16(kf, aq[1][kk], sacc[jk][1], 0, 0, 0);
      }
    }

    // ---- P = exp2(S^T + mask*log2e), bf16-trunc (l-consistent) -> sP (wave-private) ----
#pragma unroll
    for (int jk = 0; jk < 4; jk++) {
      float4 mv = *(const float4*)(sMask + kt * 64 + jk * 16 + quad * 4);  // quad-broadcast
      float m0v = mv.x * LOG2E, m1v = mv.y * LOG2E, m2v = mv.z * LOG2E, m3v = mv.w * LOG2E;
#pragma unroll
      for (int jq = 0; jq < 2; jq++) {
        unsigned u0 = __float_as_uint(__builtin_amdgcn_exp2f(sacc[jk][jq][0] + m0v)) & 0xFFFF0000u;
        unsigned u1 = __float_as_uint(__builtin_amdgcn_exp2f(sacc[jk][jq][1] + m1v)) & 0xFFFF0000u;
        unsigned u2 = __float_as_uint(__builtin_amdgcn_exp2f(sacc[jk][jq][2] + m2v)) & 0xFFFF0000u;
        unsigned u3 = __float_as_uint(__builtin_amdgcn_exp2f(sacc[jk][jq][3] + m3v)) & 0xFFFF0000u;
        lsum[jq] += (__uint_as_float(u0) + __uint_as_float(u1)) +
                    (__uint_as_float(u2) + __uint_as_float(u3));
        int2 pk;                                  // keys 4*quad..+3 pair-packed
        pk.x = (int)((u0 >> 16) | u1);
        pk.y = (int)((u2 >> 16) | u3);
        *(int2*)(sP + (wave * 32 + jq * 16 + col15) * LDP + jk * 16 + quad * 4) = pk;
      }
    }
    // no barrier: sP rows are wave-private; intra-wave LDS RAW ordered via lgkmcnt

    // ---- O^T += V^T P  (x32 MFMA: A=V^T b128, B=P^T b128) ----
#pragma unroll
    for (int jk2 = 0; jk2 < 2; jk2++) {
      short8 pf0 = *(const short8*)(sP + (wave * 32 + col15) * LDP + jk2 * 32 + quad * 8);
      short8 pf1 = *(const short8*)(sP + (wave * 32 + 16 + col15) * LDP + jk2 * 32 + quad * 8);
#pragma unroll
      for (int i = 0; i < 4; i++) {
        int row = i * 16 + col15;
        short8 vf = *(const short8*)(sVt + row * 64 + ((jk2 * 4 + quad) ^ (row & 7)) * 8);
        OT[i][0] = __builtin_amdgcn_mfma_f32_16x16x32_bf16(vf, pf0, OT[i][0], 0, 0, 0);
        OT[i][1] = __builtin_amdgcn_mfma_f32_16x16x32_bf16(vf, pf1, OT[i][1], 0, 0, 0);
      }
    }
  }

  // ---- epilogue: reduce l across quads (lanes c,c+16,c+32,c+48), O^T/l -> float4 stores ----
  float linv[2];
#pragma unroll
  for (int jq = 0; jq < 2; jq++) {
    float s_ = lsum[jq];
    s_ += __shfl_xor(s_, 16);
    s_ += __shfl_xor(s_, 32);
    linv[jq] = 1.0f / s_;
  }
#pragma unroll
  for (int jq = 0; jq < 2; jq++) {
    float* obase = out + ((size_t)b * Sn + q0 + wave * 32 + jq * 16 + col15) * Dn + h * 64 + quad * 4;
#pragma unroll
    for (int i = 0; i < 4; i++) {
      float4 o;
      o.x = OT[i][jq][0] * linv[jq];
      o.y = OT[i][jq][1] * linv[jq];
      o.z = OT[i][jq][2] * linv[jq];
      o.w = OT[i][jq][3] * linv[jq];
      *(float4*)(obase + i * 16) = o;             // d = h*64 + i*16 + quad*4 + {0..3}
    }
  }
}

extern "C" void kernel_launch(void* const* d_in, const int* in_sizes, int n_in,
                              void* d_out, int out_size, void* d_ws, size_t ws_size,
                              hipStream_t stream) {
  const float* hs   = (const float*)d_in[0];
  const float* lq   = (const float*)d_in[1];
  const float* lk   = (const float*)d_in[2];
  const float* mask = (const float*)d_in[3];
  const float* Wq   = (const float*)d_in[4];
  const float* bq   = (const float*)d_in[5];
  const float* Wk   = (const float*)d_in[6];
  const float* bk   = (const float*)d_in[7];
  const float* Wv   = (const float*)d_in[8];
  const float* bv   = (const float*)d_in[9];
  float* out = (float*)d_out;

  char* ws = (char*)d_ws;
  unsigned short* Qc = (unsigned short*)ws;          // [48][2048][128] bf16
  unsigned short* Kc = Qc + (size_t)BHn * Sn * 128;
  unsigned short* Vt = Kc + (size_t)BHn * Sn * 128;  // [48][64][2048] bf16

  proj_kernel<<<dim3(6, 64, 3), 256, 0, stream>>>(hs, Wq, Wk, Wv, bq, bk, bv, lq, lk, Qc, Kc, Vt);
  attn_kernel<<<768, 256, 0, stream>>>(Qc, Kc, Vt, mask, out);
}